// Round 10
// baseline (1597.161 us; speedup 1.0000x reference)
//
#include <hip/hip_runtime.h>
#include <math.h>

// GCN generator: B=8, N=F=128. One block/batch, 1024 threads (16 waves).
// Round 10: G carried in REGISTERS across steps (32 VGPR A-fragments, scaled
// carry C). Row/col-i patches via cndmask from s_probh; junk-diagonal handled
// algebraically: corr' = d^2(corr+1) tracked in ping-pong s_corr (f32), used
// as the epilogue identity term AND the rowsum fixup (rowsum(C) = local+corr;
// pivot row rsC(pn) = dgC exactly since untouched rows are 0 off-diag).
// No G LDS buffers: LDS 145KB -> 74KB, -160KB LDS traffic/step.
//   P2: patch+scale G regs, rowsum, mm_b z=G.u, epilogue(z,ssq,corr,X)
//   P4: mm_a u=(dv.z).W -> U || t<128: prob dots, sigmoid, out writes
//   P4c: t<128: sp butterfly, degrees -> s_d/s_df16

#define NN 128
#define SP 136

typedef _Float16 f16;
typedef _Float16 f16x8 __attribute__((ext_vector_type(8)));
typedef _Float16 f16x4 __attribute__((ext_vector_type(4)));
typedef _Float16 f16x2 __attribute__((ext_vector_type(2)));
typedef float f32x4 __attribute__((ext_vector_type(4)));

__device__ __forceinline__ f32x4 mm(f16x8 a, f16x8 b, f32x4 c) {
    return __builtin_amdgcn_mfma_f32_16x16x32_f16(a, b, c, 0, 0, 0);
}

__device__ __forceinline__ float rowdot8(f16x8 g, float acc) {
#if __has_builtin(__builtin_amdgcn_fdot2)
    const f16x2 one2 = {(f16)1.0f, (f16)1.0f};
    #pragma unroll
    for (int p = 0; p < 4; ++p) {
        f16x2 pr = {g[2*p], g[2*p+1]};
        acc = __builtin_amdgcn_fdot2(pr, one2, acc, false);
    }
#else
    #pragma unroll
    for (int e = 0; e < 8; ++e) acc += (float)g[e];
#endif
    return acc;
}

__device__ __forceinline__ float dot8(f16x8 a, f16x8 b, float acc) {
#if __has_builtin(__builtin_amdgcn_fdot2)
    #pragma unroll
    for (int p = 0; p < 4; ++p) {
        f16x2 pa = {a[2*p], a[2*p+1]};
        f16x2 pb = {b[2*p], b[2*p+1]};
        acc = __builtin_amdgcn_fdot2(pa, pb, acc, false);
    }
#else
    #pragma unroll
    for (int e = 0; e < 8; ++e) acc += (float)a[e]*(float)b[e];
#endif
    return acc;
}

__global__ __launch_bounds__(1024)
__attribute__((amdgpu_waves_per_eu(4, 4)))
void gcn_gen_kernel(const float* __restrict__ gx,
                    const float* __restrict__ gW,
                    const float* __restrict__ gb,
                    float* __restrict__ gout)
{
    extern __shared__ char lds_raw[];
    f16* X       = (f16*)lds_raw;            // [128][136] UNNORM z [n][f]
    f16* U       = X + NN*SP;                // [128][136] u = x_hat.W, [fo][m]
    f16* s_df16  = U + NN*SP;                // [128] d (f16)
    f16* s_probh = s_df16 + NN;              // [128] probs (f16)
    float* s_d     = (float*)(s_probh + NN); // [128] d (f32)
    float* s_corr  = s_d + NN;               // [2][128] corr ping-pong
    float* s_rowsC = s_corr + 2*NN;          // [128] local rowsums
    float* s_ssq   = s_rowsC + NN;           // [4][128] ssq partials by wc

    const int b = blockIdx.x;
    const int t = threadIdx.x;
    const int lane = t & 63;
    const int w = t >> 6;
    const int wr = w >> 2, wc = w & 3;       // wave grid 4x4 (32x32 tile)
    const int lrow = lane & 15;
    const int lgrp = lane >> 4;
    const int r0 = wr*32 + lrow;
    const int r1 = r0 + 16;

    const float* xb = gx + (size_t)b*NN*NN;
    float* outb = gout + (size_t)b*NN*NN;

    const float bias0 = gb[wc*32 + lrow];
    const float bias1 = gb[wc*32 + 16 + lrow];

    // ---- W -> registers as B-fragments for mm_a (k=fi, col=fo) ----
    f16x8 Wh[4][2];
    #pragma unroll
    for (int ks = 0; ks < 4; ++ks)
    #pragma unroll
    for (int ct = 0; ct < 2; ++ct) {
        const int col = wc*32 + ct*16 + lrow;
        #pragma unroll
        for (int r = 0; r < 8; ++r)
            Wh[ks][ct][r] = (f16)gW[(ks*32 + lgrp*8 + r)*NN + col];
    }

    // ---- G = I as register A-fragments (scaled carry across steps) ----
    f16x8 Gf[4][2];
    #pragma unroll
    for (int ks = 0; ks < 4; ++ks)
    #pragma unroll
    for (int rt = 0; rt < 2; ++rt)
    #pragma unroll
    for (int e = 0; e < 8; ++e)
        Gf[ks][rt][e] = (f16)((ks*32 + lgrp*8 + e == wr*32 + rt*16 + lrow) ? 1.f : 0.f);

    // ---- init: X = f16(x), out = eye, vectors ----
    #pragma unroll
    for (int q = 0; q < 16; ++q) {
        int idx = q*1024 + t;
        int r = idx >> 7, c = idx & 127;
        X[r*SP + c] = (f16)xb[idx];
        outb[idx] = (r == c) ? 1.f : 0.f;
    }
    if (t < NN) {
        s_d[t] = 0.70710678f;
        s_df16[t] = (f16)0.70710678f;
        s_corr[t] = 0.f;                     // corr_{-1} = 0 (regs hold M exactly)
    }
    __syncthreads();

    // mm_a: u = (sv . X) . W -> U[fo][m]
    auto run_mma = [&](f16 sv0, f16 sv1) {
        f32x4 a2[2][2];
        #pragma unroll
        for (int rt = 0; rt < 2; ++rt)
        #pragma unroll
        for (int ct = 0; ct < 2; ++ct)
            a2[rt][ct] = (f32x4){0.f,0.f,0.f,0.f};
        #pragma unroll
        for (int ks = 0; ks < 4; ++ks) {
            const int ko = ks*32 + lgrp*8;
            f16x8 A0 = *(const f16x8*)(X + r0*SP + ko) * sv0;
            f16x8 A1 = *(const f16x8*)(X + r1*SP + ko) * sv1;
            a2[0][0] = mm(A0, Wh[ks][0], a2[0][0]);
            a2[0][1] = mm(A0, Wh[ks][1], a2[0][1]);
            a2[1][0] = mm(A1, Wh[ks][0], a2[1][0]);
            a2[1][1] = mm(A1, Wh[ks][1], a2[1][1]);
        }
        #pragma unroll
        for (int rt = 0; rt < 2; ++rt)
        #pragma unroll
        for (int ct = 0; ct < 2; ++ct) {
            f16x4 uv;
            #pragma unroll
            for (int q = 0; q < 4; ++q) uv[q] = (f16)a2[rt][ct][q];
            *(f16x4*)(U + (wc*32 + ct*16 + lrow)*SP + wr*32 + rt*16 + lgrp*4) = uv;
        }
    };
    run_mma((f16)1.0f, (f16)1.0f);
    __syncthreads();

    for (int i = 0; i < NN; ++i) {
        const int pn = i + 1;

        // ========== P2: patch + scale G regs, rowsum, mm_b, epilogue ======
        if (i > 0) {
            // col-i patch: (r, i) = p_r for r < i
            const f16 p0 = s_probh[r0];
            const f16 p1 = s_probh[r1];
            const int ei = i & 7;
            const bool lm = (lgrp == ((i >> 3) & 3));
            const bool g0 = lm && (r0 < i);
            const bool g1 = lm && (r1 < i);
            #pragma unroll
            for (int ks = 0; ks < 4; ++ks) {
                if (ks == (i >> 5)) {            // wave-uniform branch
                    #pragma unroll
                    for (int e = 0; e < 8; ++e) {
                        Gf[ks][0][e] = (g0 && e == ei) ? p0 : Gf[ks][0][e];
                        Gf[ks][1][e] = (g1 && e == ei) ? p1 : Gf[ks][1][e];
                    }
                }
            }
            // row-i patch: (i, k) = p_k for k < i
            if (wr == (i >> 5)) {                // wave-uniform branch
                #pragma unroll
                for (int rt = 0; rt < 2; ++rt) {
                    const bool rl = ((wr*32 + rt*16 + lrow) == i);
                    #pragma unroll
                    for (int ks = 0; ks < 4; ++ks) {
                        f16x8 ph = *(const f16x8*)(s_probh + ks*32 + lgrp*8);
                        #pragma unroll
                        for (int e = 0; e < 8; ++e) {
                            const bool c = rl && (ks*32 + lgrp*8 + e < i);
                            Gf[ks][rt][e] = c ? ph[e] : Gf[ks][rt][e];
                        }
                    }
                }
            }
        }
        // scale G := G * d_col * d_row (becomes the carry C_i) + local rowsum
        {
            const f16 drh0 = s_df16[r0];
            const f16 drh1 = s_df16[r1];
            float rs0 = 0.f, rs1 = 0.f;
            #pragma unroll
            for (int ks = 0; ks < 4; ++ks) {
                const f16x8 dk = *(const f16x8*)(s_df16 + ks*32 + lgrp*8);
                Gf[ks][0] = Gf[ks][0] * dk * drh0;
                Gf[ks][1] = Gf[ks][1] * dk * drh1;
                rs0 = rowdot8(Gf[ks][0], rs0);
                rs1 = rowdot8(Gf[ks][1], rs1);
            }
            rs0 += __shfl_xor(rs0, 16); rs0 += __shfl_xor(rs0, 32);
            rs1 += __shfl_xor(rs1, 16); rs1 += __shfl_xor(rs1, 32);
            if (wc == 0 && lgrp == 0) {
                s_rowsC[r0] = rs0;
                s_rowsC[r1] = rs1;
            }
        }
        // mm_b: acc = C_i . u (A from regs, B from U)
        f32x4 acc[2][2];
        #pragma unroll
        for (int rt = 0; rt < 2; ++rt)
        #pragma unroll
        for (int ct = 0; ct < 2; ++ct)
            acc[rt][ct] = (f32x4){0.f,0.f,0.f,0.f};
        #pragma unroll
        for (int ks = 0; ks < 4; ++ks) {
            const int ko = ks*32 + lgrp*8;
            f16x8 B0 = *(const f16x8*)(U + (wc*32 + lrow)*SP + ko);
            f16x8 B1 = *(const f16x8*)(U + (wc*32 + 16 + lrow)*SP + ko);
            acc[0][0] = mm(Gf[ks][0], B0, acc[0][0]);
            acc[0][1] = mm(Gf[ks][0], B1, acc[0][1]);
            acc[1][0] = mm(Gf[ks][1], B0, acc[1][0]);
            acc[1][1] = mm(Gf[ks][1], B1, acc[1][1]);
        }
        // epilogue: z = acc + d^2(corr+1) u + bias, relu; corr update; X; ssq
        const float4 dr4a = *(const float4*)(s_d + wr*32 + lgrp*4);
        const float4 dr4b = *(const float4*)(s_d + wr*32 + 16 + lgrp*4);
        const float* cin = s_corr + (i & 1)*NN;
        float* cout = s_corr + ((i & 1) ^ 1)*NN;
        const float4 cr4a = *(const float4*)(cin + wr*32 + lgrp*4);
        const float4 cr4b = *(const float4*)(cin + wr*32 + 16 + lgrp*4);
        float cc[2][4];
        #pragma unroll
        for (int q = 0; q < 4; ++q) {
            float da = ((const float*)&dr4a)[q], db = ((const float*)&dr4b)[q];
            cc[0][q] = da*da*(((const float*)&cr4a)[q] + 1.f);
            cc[1][q] = db*db*(((const float*)&cr4b)[q] + 1.f);
        }
        float z[2][2][4];
        #pragma unroll
        for (int rt = 0; rt < 2; ++rt)
        #pragma unroll
        for (int ct = 0; ct < 2; ++ct) {
            f16x4 u4 = *(const f16x4*)(U + (wc*32 + ct*16 + lrow)*SP
                                         + wr*32 + rt*16 + lgrp*4);
            const int col = wc*32 + ct*16 + lrow;
            #pragma unroll
            for (int q = 0; q < 4; ++q) {
                float zv = fmaxf(fmaf(cc[rt][q], (float)u4[q],
                                      acc[rt][ct][q] + (ct ? bias1 : bias0)), 0.f);
                z[rt][ct][q] = zv;
                X[(wr*32 + rt*16 + lgrp*4 + q)*SP + col] = (f16)zv;
            }
        }
        if (wc == 0 && lrow == 0) {
            #pragma unroll
            for (int rt = 0; rt < 2; ++rt)
            #pragma unroll
            for (int q = 0; q < 4; ++q)
                cout[wr*32 + rt*16 + lgrp*4 + q] = cc[rt][q];
        }
        {
            float ss[8];
            #pragma unroll
            for (int k = 0; k < 8; ++k) {
                float a = z[k>>2][0][k&3], c2 = z[k>>2][1][k&3];
                ss[k] = a*a + c2*c2;
            }
            #pragma unroll
            for (int k = 0; k < 8; ++k) {
                ss[k] += __shfl_xor(ss[k], 1);
                ss[k] += __shfl_xor(ss[k], 2);
                ss[k] += __shfl_xor(ss[k], 4);
                ss[k] += __shfl_xor(ss[k], 8);
            }
            if (lrow == 0) {
                #pragma unroll
                for (int k = 0; k < 8; ++k) {
                    int row = wr*32 + (k>>2)*16 + lgrp*4 + (k&3);
                    s_ssq[wc*NN + row] = ss[k];
                }
            }
        }
        __syncthreads();

        // ========== P4: mm_a (dv-scaled, 16 waves) + t<128 prob rows ======
        float p_keep = 0.f;
        if (pn < NN) {
            f16 dvh[2];
            #pragma unroll
            for (int rt = 0; rt < 2; ++rt) {
                const int row = wr*32 + rt*16 + lrow;
                float sq = s_ssq[row] + s_ssq[NN+row] + s_ssq[2*NN+row] + s_ssq[3*NN+row];
                float dv = (i == 0) ? 1.f : 1.f/(sqrtf(sq) + 1e-8f);
                dvh[rt] = (f16)fminf(dv, 60000.f);
            }
            run_mma(dvh[0], dvh[1]);

            if (t < NN) {
                const int tt = t;
                float sqp = s_ssq[pn] + s_ssq[NN+pn] + s_ssq[2*NN+pn] + s_ssq[3*NN+pn];
                float dp = (i == 0) ? 1.f : 1.f/(sqrtf(sqp) + 1e-8f);
                if (tt < pn) {
                    const f16x8* Xr = (const f16x8*)(X + tt*SP);
                    const f16x8* Xp = (const f16x8*)(X + pn*SP);
                    float a0 = 0.f, a1 = 0.f, a2v = 0.f, a3 = 0.f;
                    #pragma unroll
                    for (int c = 0; c < 4; ++c) {
                        a0  = dot8(Xr[c*4 + 0], Xp[c*4 + 0], a0);
                        a1  = dot8(Xr[c*4 + 1], Xp[c*4 + 1], a1);
                        a2v = dot8(Xr[c*4 + 2], Xp[c*4 + 2], a2v);
                        a3  = dot8(Xr[c*4 + 3], Xp[c*4 + 3], a3);
                    }
                    float zd = (a0 + a1) + (a2v + a3);
                    float sqj = s_ssq[tt] + s_ssq[NN+tt] + s_ssq[2*NN+tt] + s_ssq[3*NN+tt];
                    float dj = (i == 0) ? 1.f : 1.f/(sqrtf(sqj) + 1e-8f);
                    p_keep = 1.f/(1.f + expf(-0.5f*zd*dj*dp));
                    outb[pn*NN + tt] = p_keep;
                    outb[tt*NN + pn] = p_keep;
                }
                s_probh[tt] = (f16)p_keep;
            }
        }
        __syncthreads();

        // ========== P4c: degrees (t<128) ==========
        if (pn < NN && t < NN) {
            const int tt = t;
            float pa = (float)s_probh[lane];
            float pb = (float)s_probh[lane + 64];
            float sp = ((lane < pn) ? pa : 0.f) + ((lane + 64 < pn) ? pb : 0.f);
            #pragma unroll
            for (int m2 = 1; m2 < 64; m2 <<= 1) sp += __shfl_xor(sp, m2);
            // rowsum(C_i) = local + corr (corr = dgC - junk; pivot row: = dgC)
            float rsC = s_rowsC[tt] + s_corr[((i & 1) ^ 1)*NN + tt];
            float rsM = rsC + ((tt < pn) ? p_keep : ((tt == pn) ? sp : 0.f));
            float dnew = 1.f/sqrtf(rsM + 1.f + 1e-8f);
            s_d[tt] = dnew;
            s_df16[tt] = (f16)dnew;
        }
        __syncthreads();
    }
}

extern "C" void kernel_launch(void* const* d_in, const int* in_sizes, int n_in,
                              void* d_out, int out_size, void* d_ws, size_t ws_size,
                              hipStream_t stream) {
    const float* x  = (const float*)d_in[0];
    const float* W  = (const float*)d_in[1];
    const float* bb = (const float*)d_in[2];
    float* out = (float*)d_out;

    const size_t shmem = (size_t)(2*NN*SP + 2*NN)*sizeof(f16)
                       + (size_t)(NN + 2*NN + NN + 4*NN)*sizeof(float);
    hipFuncSetAttribute((const void*)gcn_gen_kernel,
                        hipFuncAttributeMaxDynamicSharedMemorySize, (int)shmem);
    gcn_gen_kernel<<<8, 1024, shmem, stream>>>(x, W, bb, out);
}